// Round 1
// 611.655 us; speedup vs baseline: 1.0303x; 1.0303x over previous
//
#include <hip/hip_runtime.h>
#include <hip/hip_bf16.h>
#include <cstdint>

typedef uint16_t u16;
typedef __attribute__((ext_vector_type(8))) short short8;
typedef __attribute__((ext_vector_type(4))) float floatx4;

#define S_LEN 512
#define N_TOT 3584              // 7*512
#define HG_ROW 8388608          // 512*32*512 : flat base of row S in (S+1,B,H)
#define CT_BASE 8404992         // 513*32*512 : c_t base in out (f32 elements)

__device__ __forceinline__ float b2f(u16 u) {
  union { uint32_t i; float f; } v; v.i = ((uint32_t)u) << 16; return v.f;
}
__device__ __forceinline__ uint32_t pk2(float a, float b) {
  __hip_bfloat162 t = __float22bfloat162_rn(float2{a, b});
  return *(uint32_t*)&t;
}
__device__ __forceinline__ uint4 pack8f(const float* p) {
  const float4 x = *(const float4*)p;
  const float4 y = *(const float4*)(p + 4);
  uint4 r;
  r.x = pk2(x.x, x.y); r.y = pk2(x.z, x.w);
  r.z = pk2(y.x, y.y); r.w = pk2(y.z, y.w);
  return r;
}
__device__ __forceinline__ float sigm(float x) { return 1.f / (1.f + __expf(-x)); }
__device__ __forceinline__ float tanh_(float x) { return 2.f / (1.f + __expf(-2.f * x)) - 1.f; }
__device__ __forceinline__ int sl_stride(const int* p) { return (p[1] == 0) ? 2 : 1; }

__device__ __forceinline__ void gl_lds16(const void* g, void* l) {
  __builtin_amdgcn_global_load_lds((const __attribute__((address_space(1))) uint32_t*)g,
                                   (__attribute__((address_space(3))) uint32_t*)l, 16, 0, 0);
}

// ---- prep: hpad = [32 zero | masked bf16(h0[:-1]) | 32 zero] rows, row=(s*32+b)+32 ----
__global__ void prep_hpad(const float* __restrict__ h0, const int* __restrict__ seq_lens,
                          u16* __restrict__ hpad) {
  int i = blockIdx.x * 256 + threadIdx.x;        // 16448*64 groups of 8
  int row = i >> 6, cb = (i & 63) * 8;
  uint4 v = make_uint4(0u, 0u, 0u, 0u);
  if (row >= 32 && row < 16416) {
    int m = row - 32;
    if (((m >> 5)) < seq_lens[(m & 31) * sl_stride(seq_lens)])
      v = pack8f(h0 + (size_t)m * 512 + cb);
  }
  *(uint4*)(hpad + (size_t)row * 512 + cb) = v;
}

// ---- prep: seqs f32 -> bf16 ----
__global__ void prep_seqs(const float* __restrict__ seqs, u16* __restrict__ dst) {
  int i = blockIdx.x * 256 + threadIdx.x;        // 16384*64 groups
  size_t o = (size_t)i * 8;
  *(uint4*)(dst + o) = pack8f(seqs + o);
}

// ---- prep: Bcat[n][0:1536]=Ww[g,h,:], [1536:2048]=Wu[g,h,:]  (n=g*512+h), bf16 ----
__global__ void prep_bcat(const float* __restrict__ Ww, const float* __restrict__ Wu,
                          u16* __restrict__ Bcat) {
  int i = blockIdx.x * 256 + threadIdx.x;        // 3584*256 groups
  int n = i >> 8, col = (i & 255) * 8;
  const float* src = (col < 1536) ? Ww + (size_t)n * 1536 + col
                                  : Wu + (size_t)n * 512 + (col - 1536);
  *(uint4*)(Bcat + (size_t)n * 2048 + col) = pack8f(src);
}

// ---- prep: Bfi = bf16(Su[1]) ----
__global__ void prep_bfi(const float* __restrict__ Su, u16* __restrict__ Bfi) {
  int i = blockIdx.x * 256 + threadIdx.x;        // 512*64 groups
  size_t o = (size_t)i * 8;
  *(uint4*)(Bfi + o) = pack8f(Su + 262144 + o);
}

__global__ void k_zero(float* __restrict__ p, int n) {
  int i = blockIdx.x * 256 + threadIdx.x;
  if (i < n) p[i] = 0.f;
}

// ---- h_hat accumulation: parallel over s, atomics (hpad already masked) ----
__global__ void k_hhat(const u16* __restrict__ hpad, float* __restrict__ hhat) {
  int id = blockIdx.x * 256 + threadIdx.x;       // 16384 = b*512+h
  int b = id >> 9, h = id & 511;
  int s0 = blockIdx.y * 32;
  const u16* p = hpad + (size_t)(32 + s0 * 32 + b) * 512 + h;
  float s = 0.f;
#pragma unroll 4
  for (int i = 0; i < 32; ++i) s += b2f(p[(size_t)i * 16384]);
  atomicAdd(hhat + id, s * (1.f / 512.f));
}

// ---- small matmuls, wave-per-output, lane-split K=512, coalesced ----
__global__ void k_small(const float* __restrict__ h0, const float* __restrict__ Sw,
                        const float* __restrict__ Su, const float* __restrict__ Sb,
                        const float* __restrict__ Wv, const float* __restrict__ Wb,
                        const float* __restrict__ hhat,
                        float* __restrict__ sg0, float* __restrict__ sg2,
                        float* __restrict__ a1v, float* __restrict__ Vb) {
  int o = blockIdx.x * 4 + (threadIdx.x >> 6);   // wave id = output id (163840)
  int lane = threadIdx.x & 63;
  int k0 = lane * 8;
  const float* hg1base = h0 + (size_t)HG_ROW;
  float acc = 0.f;
  float bias;
  float* dst;
  if (o < 49152) {
    int job = o >> 14, r = o & 16383;
    int b = r >> 9, hh = r & 511;
    int widx = (job == 0) ? 0 : (job == 1) ? 2 : 1;
    const float* ar = hg1base + (size_t)b * 512 + k0;
    const float* br = Sw + ((size_t)widx * 512 + hh) * 512 + k0;
    float4 a0 = *(const float4*)ar, a1 = *(const float4*)(ar + 4);
    float4 b0 = *(const float4*)br, b1 = *(const float4*)(br + 4);
    acc = a0.x*b0.x + a0.y*b0.y + a0.z*b0.z + a0.w*b0.w
        + a1.x*b1.x + a1.y*b1.y + a1.z*b1.z + a1.w*b1.w;
    if (job != 2) {
      const float* hr = hhat + (size_t)b * 512 + k0;
      const float* ur = Su + ((size_t)widx * 512 + hh) * 512 + k0;
      float4 h0v = *(const float4*)hr, h1v = *(const float4*)(hr + 4);
      float4 u0 = *(const float4*)ur, u1 = *(const float4*)(ur + 4);
      acc += h0v.x*u0.x + h0v.y*u0.y + h0v.z*u0.z + h0v.w*u0.w
           + h1v.x*u1.x + h1v.y*u1.y + h1v.z*u1.z + h1v.w*u1.w;
    }
    bias = Sb[widx * 512 + hh];
    dst = (job == 0) ? sg0 + r : (job == 1) ? sg2 + r : a1v + r;
  } else {
    int r = o - 49152;                           // 7*16384
    int g = r >> 14, r2 = r & 16383;
    int b = r2 >> 9, n = r2 & 511;
    const float* ar = hg1base + (size_t)b * 512 + k0;
    const float* br = Wv + ((size_t)g * 512 + n) * 512 + k0;
    float4 a0 = *(const float4*)ar, a1 = *(const float4*)(ar + 4);
    float4 b0 = *(const float4*)br, b1 = *(const float4*)(br + 4);
    acc = a0.x*b0.x + a0.y*b0.y + a0.z*b0.z + a0.w*b0.w
        + a1.x*b1.x + a1.y*b1.y + a1.z*b1.z + a1.w*b1.w;
    bias = Wb[g * 512 + n];
    dst = Vb + ((size_t)g * 32 + b) * 512 + n;
  }
#pragma unroll
  for (int off2 = 32; off2 > 0; off2 >>= 1) acc += __shfl_down(acc, off2);
  if (lane == 0) *dst = acc + bias;
}

// ---- m97-style bf16 GEMM: kept for the small fi GEMM only ----
struct GemmSrc {
  const u16* a[4];   // bf16, row length 512
  const u16* b[4];   // bf16, row length bld[t]
  int bld[4];
  int bcol[4];
};

__global__ __launch_bounds__(256)
void gemm_kernel(GemmSrc ga, float* __restrict__ C, int ldc, int nblk, int m0base) {
  __shared__ __align__(16) u16 sA[128 * 32];
  __shared__ __align__(16) u16 sB[128 * 32];
  const int tid = threadIdx.x;
  const int wave = tid >> 6, lane = tid & 63;
  const int wr = wave >> 1, wc = wave & 1;
  const int lhi = lane >> 4, llo = lane & 15;
  const int m0 = blockIdx.y * 128;
  const int n0 = blockIdx.x * 128;

  const int c0i = tid, c1i = 256 + tid;          // 16B staging chunks
  const int ar0 = c0i >> 2, ac0 = (c0i & 3) * 8;
  const int ar1 = c1i >> 2, ac1 = (c1i & 3) * 8;
  u16* lA0 = sA + c0i * 8; u16* lA1 = sA + c1i * 8;
  u16* lB0 = sB + c0i * 8; u16* lB1 = sB + c1i * 8;

  floatx4 acc[4][4];
#pragma unroll
  for (int i = 0; i < 4; ++i)
#pragma unroll
    for (int j = 0; j < 4; ++j) acc[i][j] = floatx4{0.f, 0.f, 0.f, 0.f};

  for (int t = 0; t < nblk; ++t) {
    const int bld = ga.bld[t];
    const u16* ab = ga.a[t] + (size_t)(m0base + m0) * 512;
    const u16* bb = ga.b[t] + (size_t)n0 * bld + ga.bcol[t];
    const u16* pa0 = ab + (size_t)ar0 * 512 + ac0;
    const u16* pa1 = ab + (size_t)ar1 * 512 + ac1;
    const u16* pb0 = bb + (size_t)ar0 * bld + ac0;
    const u16* pb1 = bb + (size_t)ar1 * bld + ac1;
#pragma unroll 1
    for (int kk = 0; kk < 16; ++kk) {
      const int kl = kk * 32;
      __syncthreads();                           // prior iter's LDS reads done
      gl_lds16(pa0 + kl, lA0);
      gl_lds16(pa1 + kl, lA1);
      gl_lds16(pb0 + kl, lB0);
      gl_lds16(pb1 + kl, lB1);
      __syncthreads();                           // drain global_load_lds
      short8 af[4], bf[4];
#pragma unroll
      for (int i = 0; i < 4; ++i) {
        af[i] = *(const short8*)(sA + (wr * 64 + i * 16 + llo) * 32 + lhi * 8);
        bf[i] = *(const short8*)(sB + (wc * 64 + i * 16 + llo) * 32 + lhi * 8);
      }
#pragma unroll
      for (int i = 0; i < 4; ++i)
#pragma unroll
        for (int j = 0; j < 4; ++j)
          acc[i][j] = __builtin_amdgcn_mfma_f32_16x16x32_bf16(af[i], bf[j], acc[i][j], 0, 0, 0);
    }
  }

  const int rb = m0 + wr * 64 + lhi * 4;
  const int cb = n0 + wc * 64 + llo;
#pragma unroll
  for (int i = 0; i < 4; ++i)
#pragma unroll
    for (int j = 0; j < 4; ++j)
#pragma unroll
      for (int r = 0; r < 4; ++r)
        C[(size_t)(rb + i * 16 + r) * ldc + (cb + j * 16)] = acc[i][j][r];
}

// ================= 256x256 8-phase counted-vmcnt bf16 GEMM (main GEMM) ==============
// C[m,n] = sum_{kt=0..31} A_{kt>>3}[m0base+m, (kt&7)*64+..] * Bcat[n, kt*64+..]
// A blocks: t<3 -> hpad + t*16384 (rows shifted by 32/wrap pad), t==3 -> seqsb.
// 512 thr / 8 waves (2Mx4N); per-wave 128x64 out as 2x2 quadrant blocks split across
// tile halves: rows {wr*64, 128+wr*64}, cols {wc*32, 128+wc*32}. LDS 128 KiB:
// buf[2] x { A[2 halves][128x64] , B[2 halves][128x64] } bf16, st_16x32 XOR swizzle
// (byte ^= ((byte>>9)&1)<<5 within each 16 KiB half; linear gl_lds dest +
// inverse-swizzled global src + swizzled ds_read: rule #21).
// Schedule ledger (hazard-checked): group j computes kt j from buf(j&1);
//   ph1 (mb0,nb0): read A0(8)+B0(4); stage kt j+1.B1 -> nxt   [B1 of kt j-1 dead g(j-1)ph4]
//   ph2 (mb0,nb1): read B1(4);       stage kt j+1.A1 -> nxt   [A1 of kt j-1 dead g(j-1)ph4]
//   ph3 (mb1,nb0): read A1(8);       stage kt j+2.A0 -> cur   [A0 of kt j last read ph1]
//   ph4 (mb1,nb1): no reads;         stage kt j+2.B0 -> cur   [B0 of kt j last read ph1]
//   group end: s_waitcnt vmcnt(4) (kt j+1 fully landed; kt j+2.{A0,B0} = 4 loads in flight)
// Every overwrite issues in a phase strictly after (barrier-separated from) the last
// ds_read of the region it replaces; each wave's reads complete before its MFMA
// (lgkmcnt 0) which precedes the trailing barrier. K accumulation order is identical
// to the old kernel (t-major, 64-col steps, ks inner) -> bitwise-same results.

#define SWZ(b) ((b) ^ ((((b) >> 9) & 1) << 5))

#define STAGE_A(KT, H, DB) do {                                               \
    const int t_ = (KT) >> 3;                                                 \
    const u16* ab_ = (t_ == 3) ? seqsb : (hpad + ((size_t)t_ << 14));         \
    const int ko_ = ((KT) & 7) << 6;                                          \
    gl_lds16(ab_ + (size_t)(m0base + m0 + (H) * 128 + lr0) * 512 + ko_ + le0, \
             sm + (DB) * 32768 + (H) * 8192 + tid * 8);                       \
    gl_lds16(ab_ + (size_t)(m0base + m0 + (H) * 128 + lr1) * 512 + ko_ + le1, \
             sm + (DB) * 32768 + (H) * 8192 + 4096 + tid * 8);                \
  } while (0)

#define STAGE_B(KT, H, DB) do {                                               \
    gl_lds16(Bcat + (size_t)(n0 + (H) * 128 + lr0) * 2048 + (KT) * 64 + le0,  \
             sm + (DB) * 32768 + 16384 + (H) * 8192 + tid * 8);               \
    gl_lds16(Bcat + (size_t)(n0 + (H) * 128 + lr1) * 2048 + (KT) * 64 + le1,  \
             sm + (DB) * 32768 + 16384 + (H) * 8192 + 4096 + tid * 8);        \
  } while (0)

#define READ_A(DST, MB)                                                       \
  _Pragma("unroll") for (int fi = 0; fi < 4; ++fi)                            \
  _Pragma("unroll") for (int ks = 0; ks < 2; ++ks)                            \
      DST[fi][ks] = *(const short8*)(sm + curo + (MB) * 8192 + aoff[fi][ks])

#define READ_B(DST, NB)                                                       \
  _Pragma("unroll") for (int fj = 0; fj < 2; ++fj)                            \
  _Pragma("unroll") for (int ks = 0; ks < 2; ++ks)                            \
      DST[fj][ks] = *(const short8*)(sm + curo + 16384 + (NB) * 8192 + boff[fj][ks])

#define PHASE_SYNC()                                                          \
  __builtin_amdgcn_s_barrier();                                               \
  asm volatile("s_waitcnt lgkmcnt(0)" ::: "memory");                          \
  __builtin_amdgcn_sched_barrier(0)

#define MFMA_CLUSTER(MB, NB, AF, BF)                                          \
  __builtin_amdgcn_s_setprio(1);                                              \
  _Pragma("unroll") for (int fi = 0; fi < 4; ++fi)                            \
  _Pragma("unroll") for (int fj = 0; fj < 2; ++fj)                            \
  _Pragma("unroll") for (int ks = 0; ks < 2; ++ks)                            \
      acc[MB][NB][fi][fj] = __builtin_amdgcn_mfma_f32_16x16x32_bf16(          \
          AF[fi][ks], BF[fj][ks], acc[MB][NB][fi][fj], 0, 0, 0);              \
  __builtin_amdgcn_s_setprio(0)

__global__ __launch_bounds__(512, 2)
void gemm8_kernel(const u16* __restrict__ hpad, const u16* __restrict__ seqsb,
                  const u16* __restrict__ Bcat, float* __restrict__ C,
                  int m0base, int nkt) {
  __shared__ __align__(16) u16 sm[65536];        // 128 KiB
  const int tid = threadIdx.x;
  const int wave = tid >> 6, lane = tid & 63;
  const int llo = lane & 15, lhi = lane >> 4;
  const int wr = wave >> 2, wc = wave & 3;

  // XCD-aware bijective block-id swizzle (m204 formula; works for any nwg)
  const int nwg = gridDim.x * gridDim.y;
  const int lin = blockIdx.y * gridDim.x + blockIdx.x;
  const int xcd = lin & 7, idx = lin >> 3;
  const int q = nwg >> 3, r = nwg & 7;
  const int sid = (xcd < r ? xcd * (q + 1) : r * (q + 1) + (xcd - r) * q) + idx;
  const int m0 = (sid / 14) * 256;
  const int n0 = (sid % 14) * 256;

  // staging source coords: linear LDS dest chunk i*16B holds logical byte SWZ(i*16)
  const int p0 = tid * 16, p1 = (512 + tid) * 16;
  const int q0 = SWZ(p0), q1 = SWZ(p1);
  const int lr0 = q0 >> 7, le0 = (q0 & 127) >> 1;
  const int lr1 = q1 >> 7, le1 = (q1 & 127) >> 1;

  // swizzled fragment read offsets (u16 units), half-relative
  int aoff[4][2], boff[2][2];
#pragma unroll
  for (int fi = 0; fi < 4; ++fi)
#pragma unroll
    for (int ks = 0; ks < 2; ++ks) {
      int by = (wr * 64 + fi * 16 + llo) * 128 + ks * 64 + lhi * 16;
      aoff[fi][ks] = SWZ(by) >> 1;
    }
#pragma unroll
  for (int fj = 0; fj < 2; ++fj)
#pragma unroll
    for (int ks = 0; ks < 2; ++ks) {
      int by = (wc * 32 + fj * 16 + llo) * 128 + ks * 64 + lhi * 16;
      boff[fj][ks] = SWZ(by) >> 1;
    }

  floatx4 acc[2][2][4][2];
#pragma unroll
  for (int mb = 0; mb < 2; ++mb)
#pragma unroll
    for (int nb = 0; nb < 2; ++nb)
#pragma unroll
      for (int fi = 0; fi < 4; ++fi)
#pragma unroll
        for (int fj = 0; fj < 2; ++fj)
          acc[mb][nb][fi][fj] = floatx4{0.f, 0.f, 0.f, 0.f};

  // prologue: kt0 fully + kt1.{A0,B0}; vmcnt(4) -> kt0 landed, 2 halves in flight
  STAGE_A(0, 0, 0); STAGE_B(0, 0, 0); STAGE_B(0, 1, 0); STAGE_A(0, 1, 0);
  STAGE_A(1, 0, 1); STAGE_B(1, 0, 1);
  asm volatile("s_waitcnt vmcnt(4)" ::: "memory");
  __builtin_amdgcn_s_barrier();

  short8 af[4][2], b0f[2][2], b1f[2][2];
  for (int j = 0; j < nkt; ++j) {
    const int cur = j & 1, nxt = cur ^ 1;
    const int curo = cur * 32768;
    // ---- ph1 (mb0, nb0) ----
    READ_A(af, 0);
    READ_B(b0f, 0);
    if (j + 1 < nkt) STAGE_B(j + 1, 1, nxt);
    PHASE_SYNC();
    MFMA_CLUSTER(0, 0, af, b0f);
    __builtin_amdgcn_s_barrier();
    // ---- ph2 (mb0, nb1) ----
    READ_B(b1f, 1);
    if (j + 1 < nkt) STAGE_A(j + 1, 1, nxt);
    PHASE_SYNC();
    MFMA_CLUSTER(0, 1, af, b1f);
    __builtin_amdgcn_s_barrier();
    // ---- ph3 (mb1, nb0) ----
    READ_A(af, 1);
    if (j + 2 < nkt) STAGE_A(j + 2, 0, cur);
    PHASE_SYNC();
    MFMA_CLUSTER(1, 0, af, b0f);
    __builtin_amdgcn_s_barrier();
    // ---- ph4 (mb1, nb1) ----
    if (j + 2 < nkt) STAGE_B(j + 2, 0, cur);
    PHASE_SYNC();
    MFMA_CLUSTER(1, 1, af, b1f);
    if (j < nkt - 2) asm volatile("s_waitcnt vmcnt(4)" ::: "memory");
    else             asm volatile("s_waitcnt vmcnt(0)" ::: "memory");
    __builtin_amdgcn_s_barrier();
  }

#pragma unroll
  for (int mb = 0; mb < 2; ++mb)
#pragma unroll
    for (int nb = 0; nb < 2; ++nb)
#pragma unroll
      for (int fi = 0; fi < 4; ++fi)
#pragma unroll
        for (int fj = 0; fj < 2; ++fj)
#pragma unroll
          for (int rr = 0; rr < 4; ++rr)
            C[(size_t)(m0 + mb * 128 + wr * 64 + fi * 16 + lhi * 4 + rr) * N_TOT
              + (n0 + nb * 128 + wc * 32 + fj * 16 + llo)] = acc[mb][nb][fi][fj][rr];
}

// ---- fi softmax-weighted reduction over s (chunked partials + atomics) ----
__global__ void k_fireduce(const float* __restrict__ Cfi, const float* __restrict__ a1v,
                           const float* __restrict__ c0, const int* __restrict__ seq_lens,
                           float* __restrict__ denom, float* __restrict__ cacc,
                           int sbase, int send) {
  int id = blockIdx.x * 256 + threadIdx.x;       // b*512+h
  int b = id >> 9, h = id & 511;
  int len = seq_lens[b * sl_stride(seq_lens)];
  int lim = (send < len) ? send : len;
  int s0 = sbase + blockIdx.y * 64;
  if (s0 >= lim) return;
  int s1 = (s0 + 64 < lim) ? s0 + 64 : lim;
  float a = a1v[id];
  float d = 0.f, ca = 0.f;
  for (int s = s0; s < s1; ++s) {
    size_t m = (size_t)(s * 32 + b);
    size_t ml = (size_t)((s - sbase) * 32 + b);
    float e = __expf(sigm(Cfi[ml * 512 + h] + a));
    d += e;
    ca += e * c0[m * 512 + h];
  }
  atomicAdd(&denom[id], d);
  atomicAdd(&cacc[id], ca);
}

// ---- global cell: c_g, h_g → out row S ----
__global__ void k_global(const float* __restrict__ sg0, const float* __restrict__ sg2,
                         const float* __restrict__ c0, const float* __restrict__ denom,
                         const float* __restrict__ cacc, float* __restrict__ out) {
  int id = blockIdx.x * 256 + threadIdx.x;       // 16384
  float fg = sigm(sg0[id]);
  float og = sigm(sg2[id]);
  float cg1 = c0[(size_t)HG_ROW + id];
  float dn = denom[id];
  float cg = fg * cg1 + cacc[id] / (dn > 0.f ? dn : 1.f);
  float hg = og * tanh_(cg);
  out[(size_t)HG_ROW + id] = hg;
  out[(size_t)CT_BASE + HG_ROW + id] = cg;
}

// ---- window epilogue: gates softmax-5, c_w, h_w ----
__global__ void k_epilogue(const float* __restrict__ Cch, const float* __restrict__ Vb,
                           const float* __restrict__ c0, const int* __restrict__ seq_lens,
                           float* __restrict__ out, int mbase) {
  int idx = blockIdx.x * 256 + threadIdx.x;      // chunk-local (m,h)
  int ml = idx >> 9, h = idx & 511;
  int mg = mbase + ml;
  int s = mg >> 5, b = mg & 31;
  int len = seq_lens[b * sl_stride(seq_lens)];
  float pre[7];
#pragma unroll
  for (int g = 0; g < 7; ++g)
    pre[g] = Cch[(size_t)ml * N_TOT + g * 512 + h] + Vb[(size_t)(g * 32 + b) * 512 + h];
  float i_ = sigm(pre[0]);
  float l_ = sigm(pre[1]);
  float r_ = sigm(pre[2]);
  float f_ = sigm(pre[3]);
  float sg = sigm(pre[4]);
  float o_ = sigm(pre[5]);
  float u_ = tanh_(pre[6]);
  float el = __expf(l_), ef = __expf(f_), er = __expf(r_), es = __expf(sg), ei = __expf(i_);
  float inv = 1.f / (el + ef + er + es + ei);
  float cw = 0.f;
  if (s < len) {
    float cl = (s >= 1) ? c0[(size_t)(mg - 32) * 512 + h] : 0.f;
    float cc = c0[(size_t)mg * 512 + h];
    float cr = (s + 1 < S_LEN && s + 1 < len) ? c0[(size_t)(mg + 32) * 512 + h] : 0.f;
    float cg1 = c0[(size_t)HG_ROW + b * 512 + h];
    cw = (el * cl + ef * cc + er * cr + es * cg1 + ei * u_) * inv;
  }
  float hw = o_ * tanh_(cw);
  size_t oi = (size_t)mg * 512 + h;
  out[oi] = hw;
  out[(size_t)CT_BASE + oi] = cw;
}

extern "C" void kernel_launch(void* const* d_in, const int* in_sizes, int n_in,
                              void* d_out, int out_size, void* d_ws, size_t ws_size,
                              hipStream_t stream) {
  const float* seqs = (const float*)d_in[0];
  const int* seq_lens = (const int*)d_in[1];
  const float* h0 = (const float*)d_in[2];
  const float* c0 = (const float*)d_in[3];
  const float* Ww = (const float*)d_in[4];
  const float* Wu = (const float*)d_in[5];
  const float* Wv = (const float*)d_in[6];
  const float* Wb = (const float*)d_in[7];
  const float* Sw = (const float*)d_in[8];
  const float* Su = (const float*)d_in[9];
  const float* Sb = (const float*)d_in[10];
  float* out = (float*)d_out;

  // ---- workspace layout (fixed ~49.7 MB) + adaptive C chunk ----
  char* ws = (char*)d_ws;
  size_t off = 0;
  float* denom = (float*)(ws + off); off += 16384 * 4;   // zeroed together:
  float* cacc  = (float*)(ws + off); off += 16384 * 4;   // denom, cacc, hhat
  float* hhat  = (float*)(ws + off); off += 16384 * 4;
  float* sg0  = (float*)(ws + off); off += 16384 * 4;
  float* sg2  = (float*)(ws + off); off += 16384 * 4;
  float* a1v  = (float*)(ws + off); off += 16384 * 4;
  float* Vb   = (float*)(ws + off); off += (size_t)7 * 16384 * 4;
  u16* hpad  = (u16*)(ws + off); off += (size_t)16448 * 512 * 2;   // 16.84 MB
  u16* seqsb = (u16*)(ws + off); off += (size_t)16384 * 512 * 2;   // 16.78 MB
  u16* Bcat  = (u16*)(ws + off); off += (size_t)3584 * 2048 * 2;   // 14.68 MB
  u16* Bfi   = (u16*)(ws + off); off += (size_t)512 * 512 * 2;     //  0.52 MB
  float* Cbig = (float*)(ws + off);

  size_t avail = (ws_size > off) ? (ws_size - off) : 0;
  int chunk_rows = (int)(avail / ((size_t)N_TOT * 4));
  chunk_rows = (chunk_rows / 256) * 256;         // 256-row tiles for gemm8
  if (chunk_rows > 4096) chunk_rows = 4096;
  if (chunk_rows < 256) chunk_rows = 256;
  int fi_rows = 7 * chunk_rows;                  // same byte budget at ldc=512
  if (fi_rows > 16384) fi_rows = 16384;

  prep_hpad<<<4112, 256, 0, stream>>>(h0, seq_lens, hpad);
  prep_seqs<<<4096, 256, 0, stream>>>(seqs, seqsb);
  prep_bcat<<<3584, 256, 0, stream>>>(Ww, Wu, Bcat);
  prep_bfi<<<128, 256, 0, stream>>>(Su, Bfi);
  k_zero<<<192, 256, 0, stream>>>(denom, 49152);          // denom+cacc+hhat
  k_hhat<<<dim3(64, 16), 256, 0, stream>>>(hpad, hhat);
  k_small<<<40960, 256, 0, stream>>>(h0, Sw, Su, Sb, Wv, Wb, hhat, sg0, sg2, a1v, Vb);

  // fi GEMM (16384 x 512) = h_w1 @ Su[1]^T, chunked over rows (old 128^2 kernel)
  GemmSrc gfi;
  gfi.a[0] = hpad + 32 * 512; gfi.b[0] = Bfi; gfi.bld[0] = 512; gfi.bcol[0] = 0;
  for (int fb = 0; fb < 16384; fb += fi_rows) {
    int rows = (fi_rows < 16384 - fb) ? fi_rows : (16384 - fb);
    gemm_kernel<<<dim3(4, rows / 128), 256, 0, stream>>>(gfi, Cbig, 512, 1, fb);
    int sbase = fb / 32, scnt = rows / 32;
    k_fireduce<<<dim3(64, (scnt + 63) / 64), 256, 0, stream>>>(
        Cbig, a1v, c0, seq_lens, denom, cacc, sbase, sbase + scnt);
  }
  k_global<<<64, 256, 0, stream>>>(sg0, sg2, c0, denom, cacc, out);

  // main GEMM: 8-phase 256^2 kernel; K = {h_w1[s-1], h_w1[s], h_w1[s+1], seqs} x Bcat
  for (int mb = 0; mb < 16384; mb += chunk_rows) {
    int rows = (chunk_rows < 16384 - mb) ? chunk_rows : (16384 - mb);
    gemm8_kernel<<<dim3(14, rows / 256), 512, 0, stream>>>(hpad, seqsb, Bcat, Cbig, mb, 32);
    k_epilogue<<<rows * 2, 256, 0, stream>>>(Cbig, Vb, c0, seq_lens, out, mb);
  }
}

// Round 2
// 587.407 us; speedup vs baseline: 1.0728x; 1.0413x over previous
//
#include <hip/hip_runtime.h>
#include <hip/hip_bf16.h>
#include <cstdint>

typedef uint16_t u16;
typedef __attribute__((ext_vector_type(8))) short short8;
typedef __attribute__((ext_vector_type(4))) float floatx4;

#define S_LEN 512
#define N_TOT 3584              // 7*512
#define HG_ROW 8388608          // 512*32*512 : flat base of row S in (S+1,B,H)
#define CT_BASE 8404992         // 513*32*512 : c_t base in out (f32 elements)

__device__ __forceinline__ float b2f(u16 u) {
  union { uint32_t i; float f; } v; v.i = ((uint32_t)u) << 16; return v.f;
}
__device__ __forceinline__ uint32_t pk2(float a, float b) {
  __hip_bfloat162 t = __float22bfloat162_rn(float2{a, b});
  return *(uint32_t*)&t;
}
__device__ __forceinline__ uint4 pack8f(const float* p) {
  const float4 x = *(const float4*)p;
  const float4 y = *(const float4*)(p + 4);
  uint4 r;
  r.x = pk2(x.x, x.y); r.y = pk2(x.z, x.w);
  r.z = pk2(y.x, y.y); r.w = pk2(y.z, y.w);
  return r;
}
__device__ __forceinline__ float sigm(float x) { return 1.f / (1.f + __expf(-x)); }
__device__ __forceinline__ float tanh_(float x) { return 2.f / (1.f + __expf(-2.f * x)) - 1.f; }
__device__ __forceinline__ int sl_stride(const int* p) { return (p[1] == 0) ? 2 : 1; }

__device__ __forceinline__ void gl_lds16(const void* g, void* l) {
  __builtin_amdgcn_global_load_lds((const __attribute__((address_space(1))) uint32_t*)g,
                                   (__attribute__((address_space(3))) uint32_t*)l, 16, 0, 0);
}

// ---- prep: hpad = [32 zero | masked bf16(h0[:-1]) | 32 zero] rows, row=(s*32+b)+32 ----
__global__ void prep_hpad(const float* __restrict__ h0, const int* __restrict__ seq_lens,
                          u16* __restrict__ hpad) {
  int i = blockIdx.x * 256 + threadIdx.x;        // 16448*64 groups of 8
  int row = i >> 6, cb = (i & 63) * 8;
  uint4 v = make_uint4(0u, 0u, 0u, 0u);
  if (row >= 32 && row < 16416) {
    int m = row - 32;
    if (((m >> 5)) < seq_lens[(m & 31) * sl_stride(seq_lens)])
      v = pack8f(h0 + (size_t)m * 512 + cb);
  }
  *(uint4*)(hpad + (size_t)row * 512 + cb) = v;
}

// ---- prep: seqs f32 -> bf16 ----
__global__ void prep_seqs(const float* __restrict__ seqs, u16* __restrict__ dst) {
  int i = blockIdx.x * 256 + threadIdx.x;        // 16384*64 groups
  size_t o = (size_t)i * 8;
  *(uint4*)(dst + o) = pack8f(seqs + o);
}

// ---- prep: Bcat[n][0:1536]=Ww[g,h,:], [1536:2048]=Wu[g,h,:]  (n=g*512+h), bf16 ----
__global__ void prep_bcat(const float* __restrict__ Ww, const float* __restrict__ Wu,
                          u16* __restrict__ Bcat) {
  int i = blockIdx.x * 256 + threadIdx.x;        // 3584*256 groups
  int n = i >> 8, col = (i & 255) * 8;
  const float* src = (col < 1536) ? Ww + (size_t)n * 1536 + col
                                  : Wu + (size_t)n * 512 + (col - 1536);
  *(uint4*)(Bcat + (size_t)n * 2048 + col) = pack8f(src);
}

// ---- prep: Bfi = bf16(Su[1]) ----
__global__ void prep_bfi(const float* __restrict__ Su, u16* __restrict__ Bfi) {
  int i = blockIdx.x * 256 + threadIdx.x;        // 512*64 groups
  size_t o = (size_t)i * 8;
  *(uint4*)(Bfi + o) = pack8f(Su + 262144 + o);
}

__global__ void k_zero(float* __restrict__ p, int n) {
  int i = blockIdx.x * 256 + threadIdx.x;
  if (i < n) p[i] = 0.f;
}

// ---- h_hat accumulation: parallel over s, atomics (hpad already masked) ----
__global__ void k_hhat(const u16* __restrict__ hpad, float* __restrict__ hhat) {
  int id = blockIdx.x * 256 + threadIdx.x;       // 16384 = b*512+h
  int b = id >> 9, h = id & 511;
  int s0 = blockIdx.y * 32;
  const u16* p = hpad + (size_t)(32 + s0 * 32 + b) * 512 + h;
  float s = 0.f;
#pragma unroll 4
  for (int i = 0; i < 32; ++i) s += b2f(p[(size_t)i * 16384]);
  atomicAdd(hhat + id, s * (1.f / 512.f));
}

// ---- small matmuls, wave-per-output, lane-split K=512, coalesced ----
__global__ void k_small(const float* __restrict__ h0, const float* __restrict__ Sw,
                        const float* __restrict__ Su, const float* __restrict__ Sb,
                        const float* __restrict__ Wv, const float* __restrict__ Wb,
                        const float* __restrict__ hhat,
                        float* __restrict__ sg0, float* __restrict__ sg2,
                        float* __restrict__ a1v, float* __restrict__ Vb) {
  int o = blockIdx.x * 4 + (threadIdx.x >> 6);   // wave id = output id (163840)
  int lane = threadIdx.x & 63;
  int k0 = lane * 8;
  const float* hg1base = h0 + (size_t)HG_ROW;
  float acc = 0.f;
  float bias;
  float* dst;
  if (o < 49152) {
    int job = o >> 14, r = o & 16383;
    int b = r >> 9, hh = r & 511;
    int widx = (job == 0) ? 0 : (job == 1) ? 2 : 1;
    const float* ar = hg1base + (size_t)b * 512 + k0;
    const float* br = Sw + ((size_t)widx * 512 + hh) * 512 + k0;
    float4 a0 = *(const float4*)ar, a1 = *(const float4*)(ar + 4);
    float4 b0 = *(const float4*)br, b1 = *(const float4*)(br + 4);
    acc = a0.x*b0.x + a0.y*b0.y + a0.z*b0.z + a0.w*b0.w
        + a1.x*b1.x + a1.y*b1.y + a1.z*b1.z + a1.w*b1.w;
    if (job != 2) {
      const float* hr = hhat + (size_t)b * 512 + k0;
      const float* ur = Su + ((size_t)widx * 512 + hh) * 512 + k0;
      float4 h0v = *(const float4*)hr, h1v = *(const float4*)(hr + 4);
      float4 u0 = *(const float4*)ur, u1 = *(const float4*)(ur + 4);
      acc += h0v.x*u0.x + h0v.y*u0.y + h0v.z*u0.z + h0v.w*u0.w
           + h1v.x*u1.x + h1v.y*u1.y + h1v.z*u1.z + h1v.w*u1.w;
    }
    bias = Sb[widx * 512 + hh];
    dst = (job == 0) ? sg0 + r : (job == 1) ? sg2 + r : a1v + r;
  } else {
    int r = o - 49152;                           // 7*16384
    int g = r >> 14, r2 = r & 16383;
    int b = r2 >> 9, n = r2 & 511;
    const float* ar = hg1base + (size_t)b * 512 + k0;
    const float* br = Wv + ((size_t)g * 512 + n) * 512 + k0;
    float4 a0 = *(const float4*)ar, a1 = *(const float4*)(ar + 4);
    float4 b0 = *(const float4*)br, b1 = *(const float4*)(br + 4);
    acc = a0.x*b0.x + a0.y*b0.y + a0.z*b0.z + a0.w*b0.w
        + a1.x*b1.x + a1.y*b1.y + a1.z*b1.z + a1.w*b1.w;
    bias = Wb[g * 512 + n];
    dst = Vb + ((size_t)g * 32 + b) * 512 + n;
  }
#pragma unroll
  for (int off2 = 32; off2 > 0; off2 >>= 1) acc += __shfl_down(acc, off2);
  if (lane == 0) *dst = acc + bias;
}

// ---- m97-style bf16 GEMM: kept for the small fi GEMM only ----
struct GemmSrc {
  const u16* a[4];   // bf16, row length 512
  const u16* b[4];   // bf16, row length bld[t]
  int bld[4];
  int bcol[4];
};

__global__ __launch_bounds__(256)
void gemm_kernel(GemmSrc ga, float* __restrict__ C, int ldc, int nblk, int m0base) {
  __shared__ __align__(16) u16 sA[128 * 32];
  __shared__ __align__(16) u16 sB[128 * 32];
  const int tid = threadIdx.x;
  const int wave = tid >> 6, lane = tid & 63;
  const int wr = wave >> 1, wc = wave & 1;
  const int lhi = lane >> 4, llo = lane & 15;
  const int m0 = blockIdx.y * 128;
  const int n0 = blockIdx.x * 128;

  const int c0i = tid, c1i = 256 + tid;          // 16B staging chunks
  const int ar0 = c0i >> 2, ac0 = (c0i & 3) * 8;
  const int ar1 = c1i >> 2, ac1 = (c1i & 3) * 8;
  u16* lA0 = sA + c0i * 8; u16* lA1 = sA + c1i * 8;
  u16* lB0 = sB + c0i * 8; u16* lB1 = sB + c1i * 8;

  floatx4 acc[4][4];
#pragma unroll
  for (int i = 0; i < 4; ++i)
#pragma unroll
    for (int j = 0; j < 4; ++j) acc[i][j] = floatx4{0.f, 0.f, 0.f, 0.f};

  for (int t = 0; t < nblk; ++t) {
    const int bld = ga.bld[t];
    const u16* ab = ga.a[t] + (size_t)(m0base + m0) * 512;
    const u16* bb = ga.b[t] + (size_t)n0 * bld + ga.bcol[t];
    const u16* pa0 = ab + (size_t)ar0 * 512 + ac0;
    const u16* pa1 = ab + (size_t)ar1 * 512 + ac1;
    const u16* pb0 = bb + (size_t)ar0 * bld + ac0;
    const u16* pb1 = bb + (size_t)ar1 * bld + ac1;
#pragma unroll 1
    for (int kk = 0; kk < 16; ++kk) {
      const int kl = kk * 32;
      __syncthreads();                           // prior iter's LDS reads done
      gl_lds16(pa0 + kl, lA0);
      gl_lds16(pa1 + kl, lA1);
      gl_lds16(pb0 + kl, lB0);
      gl_lds16(pb1 + kl, lB1);
      __syncthreads();                           // drain global_load_lds
      short8 af[4], bf[4];
#pragma unroll
      for (int i = 0; i < 4; ++i) {
        af[i] = *(const short8*)(sA + (wr * 64 + i * 16 + llo) * 32 + lhi * 8);
        bf[i] = *(const short8*)(sB + (wc * 64 + i * 16 + llo) * 32 + lhi * 8);
      }
#pragma unroll
      for (int i = 0; i < 4; ++i)
#pragma unroll
        for (int j = 0; j < 4; ++j)
          acc[i][j] = __builtin_amdgcn_mfma_f32_16x16x32_bf16(af[i], bf[j], acc[i][j], 0, 0, 0);
    }
  }

  const int rb = m0 + wr * 64 + lhi * 4;
  const int cb = n0 + wc * 64 + llo;
#pragma unroll
  for (int i = 0; i < 4; ++i)
#pragma unroll
    for (int j = 0; j < 4; ++j)
#pragma unroll
      for (int r = 0; r < 4; ++r)
        C[(size_t)(rb + i * 16 + r) * ldc + (cb + j * 16)] = acc[i][j][r];
}

// ================= 256x256 8-phase counted-vmcnt bf16 GEMM (main GEMM) ==============
// C[m,n] = sum_{kt=0..31} A_{kt>>3}[m0base+m, (kt&7)*64+..] * Bcat[n, kt*64+..]
// A blocks: t<3 -> hpad + t*16384 (rows shifted by 32/wrap pad), t==3 -> seqsb.
// 512 thr / 8 waves (2Mx4N); per-wave 128x64 out as 2x2 quadrant blocks split across
// tile halves: rows {wr*64, 128+wr*64}, cols {wc*32, 128+wc*32}. LDS 128 KiB:
// buf[2] x { A[2 halves][128x64] , B[2 halves][128x64] } bf16.
//
// SWIZZLE (round-1 fix): bank slot = byte mod 128 (row stride = exactly 128 B, rows
// never shift banks). Fragment reads sit at slot lhi+4*ks -> only 4 of 8 slots,
// 16 lanes/slot = 4-way conflict (measured 5.5M/dispatch). Old SWZ (bit9->bit5) only
// permuted within those 4 slots. New: XOR row bits 0-2 into slot bits 4-6
// (G4 attn form, 128B rows):  b ^= ((b>>7)&7)<<4.  Read slot becomes
// (lhi+4ks)^(llo&7): all 8 slots x 8 lanes = conflict-free minimum for b128.
// Involution, preserves bits 0-3 -> 16B-chunk permutation; linear gl_lds dest +
// inverse-swizzled global source + swizzled ds_read (rule #21) unchanged otherwise.
//
// Schedule ledger (hazard-checked): group j computes kt j from buf(j&1);
//   ph1 (mb0,nb0): read A0(8)+B0(4); stage kt j+1.B1 -> nxt   [B1 of kt j-1 dead g(j-1)ph4]
//   ph2 (mb0,nb1): read B1(4);       stage kt j+1.A1 -> nxt   [A1 of kt j-1 dead g(j-1)ph4]
//   ph3 (mb1,nb0): read A1(8);       stage kt j+2.A0 -> cur   [A0 of kt j last read ph1]
//   ph4 (mb1,nb1): no reads;         stage kt j+2.B0 -> cur   [B0 of kt j last read ph1]
//   group end: s_waitcnt vmcnt(4) (kt j+1 fully landed; kt j+2.{A0,B0} = 4 loads in flight)
// K accumulation order identical to the old kernel -> bitwise-same results.

#define SWZ(b) ((b) ^ ((((b) >> 7) & 7) << 4))

#define STAGE_A(KT, H, DB) do {                                               \
    const int t_ = (KT) >> 3;                                                 \
    const u16* ab_ = (t_ == 3) ? seqsb : (hpad + ((size_t)t_ << 14));         \
    const int ko_ = ((KT) & 7) << 6;                                          \
    gl_lds16(ab_ + (size_t)(m0base + m0 + (H) * 128 + lr0) * 512 + ko_ + le0, \
             sm + (DB) * 32768 + (H) * 8192 + tid * 8);                       \
    gl_lds16(ab_ + (size_t)(m0base + m0 + (H) * 128 + lr1) * 512 + ko_ + le1, \
             sm + (DB) * 32768 + (H) * 8192 + 4096 + tid * 8);                \
  } while (0)

#define STAGE_B(KT, H, DB) do {                                               \
    gl_lds16(Bcat + (size_t)(n0 + (H) * 128 + lr0) * 2048 + (KT) * 64 + le0,  \
             sm + (DB) * 32768 + 16384 + (H) * 8192 + tid * 8);               \
    gl_lds16(Bcat + (size_t)(n0 + (H) * 128 + lr1) * 2048 + (KT) * 64 + le1,  \
             sm + (DB) * 32768 + 16384 + (H) * 8192 + 4096 + tid * 8);        \
  } while (0)

#define READ_A(DST, MB)                                                       \
  _Pragma("unroll") for (int fi = 0; fi < 4; ++fi)                            \
  _Pragma("unroll") for (int ks = 0; ks < 2; ++ks)                            \
      DST[fi][ks] = *(const short8*)(sm + curo + (MB) * 8192 + aoff[fi][ks])

#define READ_B(DST, NB)                                                       \
  _Pragma("unroll") for (int fj = 0; fj < 2; ++fj)                            \
  _Pragma("unroll") for (int ks = 0; ks < 2; ++ks)                            \
      DST[fj][ks] = *(const short8*)(sm + curo + 16384 + (NB) * 8192 + boff[fj][ks])

#define PHASE_SYNC()                                                          \
  __builtin_amdgcn_s_barrier();                                               \
  asm volatile("s_waitcnt lgkmcnt(0)" ::: "memory");                          \
  __builtin_amdgcn_sched_barrier(0)

#define MFMA_CLUSTER(MB, NB, AF, BF)                                          \
  __builtin_amdgcn_s_setprio(1);                                              \
  _Pragma("unroll") for (int fi = 0; fi < 4; ++fi)                            \
  _Pragma("unroll") for (int fj = 0; fj < 2; ++fj)                            \
  _Pragma("unroll") for (int ks = 0; ks < 2; ++ks)                            \
      acc[MB][NB][fi][fj] = __builtin_amdgcn_mfma_f32_16x16x32_bf16(          \
          AF[fi][ks], BF[fj][ks], acc[MB][NB][fi][fj], 0, 0, 0);              \
  __builtin_amdgcn_s_setprio(0)

__global__ __launch_bounds__(512, 2)
void gemm8_kernel(const u16* __restrict__ hpad, const u16* __restrict__ seqsb,
                  const u16* __restrict__ Bcat, float* __restrict__ C,
                  int m0base, int nkt) {
  __shared__ __align__(16) u16 sm[65536];        // 128 KiB
  const int tid = threadIdx.x;
  const int wave = tid >> 6, lane = tid & 63;
  const int llo = lane & 15, lhi = lane >> 4;
  const int wr = wave >> 2, wc = wave & 3;

  // XCD-aware bijective block-id swizzle (m204 formula; works for any nwg)
  const int nwg = gridDim.x * gridDim.y;
  const int lin = blockIdx.y * gridDim.x + blockIdx.x;
  const int xcd = lin & 7, idx = lin >> 3;
  const int q = nwg >> 3, r = nwg & 7;
  const int sid = (xcd < r ? xcd * (q + 1) : r * (q + 1) + (xcd - r) * q) + idx;
  const int m0 = (sid / 14) * 256;
  const int n0 = (sid % 14) * 256;

  // staging source coords: linear LDS dest chunk i*16B holds logical byte SWZ(i*16)
  const int p0 = tid * 16, p1 = (512 + tid) * 16;
  const int q0 = SWZ(p0), q1 = SWZ(p1);
  const int lr0 = q0 >> 7, le0 = (q0 & 127) >> 1;
  const int lr1 = q1 >> 7, le1 = (q1 & 127) >> 1;

  // swizzled fragment read offsets (u16 units), half-relative
  int aoff[4][2], boff[2][2];
#pragma unroll
  for (int fi = 0; fi < 4; ++fi)
#pragma unroll
    for (int ks = 0; ks < 2; ++ks) {
      int by = (wr * 64 + fi * 16 + llo) * 128 + ks * 64 + lhi * 16;
      aoff[fi][ks] = SWZ(by) >> 1;
    }
#pragma unroll
  for (int fj = 0; fj < 2; ++fj)
#pragma unroll
    for (int ks = 0; ks < 2; ++ks) {
      int by = (wc * 32 + fj * 16 + llo) * 128 + ks * 64 + lhi * 16;
      boff[fj][ks] = SWZ(by) >> 1;
    }

  floatx4 acc[2][2][4][2];
#pragma unroll
  for (int mb = 0; mb < 2; ++mb)
#pragma unroll
    for (int nb = 0; nb < 2; ++nb)
#pragma unroll
      for (int fi = 0; fi < 4; ++fi)
#pragma unroll
        for (int fj = 0; fj < 2; ++fj)
          acc[mb][nb][fi][fj] = floatx4{0.f, 0.f, 0.f, 0.f};

  // prologue: kt0 fully + kt1.{A0,B0}; vmcnt(4) -> kt0 landed, 2 halves in flight
  STAGE_A(0, 0, 0); STAGE_B(0, 0, 0); STAGE_B(0, 1, 0); STAGE_A(0, 1, 0);
  STAGE_A(1, 0, 1); STAGE_B(1, 0, 1);
  asm volatile("s_waitcnt vmcnt(4)" ::: "memory");
  __builtin_amdgcn_s_barrier();

  short8 af[4][2], b0f[2][2], b1f[2][2];
  for (int j = 0; j < nkt; ++j) {
    const int cur = j & 1, nxt = cur ^ 1;
    const int curo = cur * 32768;
    // ---- ph1 (mb0, nb0) ----
    READ_A(af, 0);
    READ_B(b0f, 0);
    if (j + 1 < nkt) STAGE_B(j + 1, 1, nxt);
    PHASE_SYNC();
    MFMA_CLUSTER(0, 0, af, b0f);
    __builtin_amdgcn_s_barrier();
    // ---- ph2 (mb0, nb1) ----
    READ_B(b1f, 1);
    if (j + 1 < nkt) STAGE_A(j + 1, 1, nxt);
    PHASE_SYNC();
    MFMA_CLUSTER(0, 1, af, b1f);
    __builtin_amdgcn_s_barrier();
    // ---- ph3 (mb1, nb0) ----
    READ_A(af, 1);
    if (j + 2 < nkt) STAGE_A(j + 2, 0, cur);
    PHASE_SYNC();
    MFMA_CLUSTER(1, 0, af, b0f);
    __builtin_amdgcn_s_barrier();
    // ---- ph4 (mb1, nb1) ----
    if (j + 2 < nkt) STAGE_B(j + 2, 0, cur);
    PHASE_SYNC();
    MFMA_CLUSTER(1, 1, af, b1f);
    if (j < nkt - 2) asm volatile("s_waitcnt vmcnt(4)" ::: "memory");
    else             asm volatile("s_waitcnt vmcnt(0)" ::: "memory");
    __builtin_amdgcn_s_barrier();
  }

#pragma unroll
  for (int mb = 0; mb < 2; ++mb)
#pragma unroll
    for (int nb = 0; nb < 2; ++nb)
#pragma unroll
      for (int fi = 0; fi < 4; ++fi)
#pragma unroll
        for (int fj = 0; fj < 2; ++fj)
#pragma unroll
          for (int rr = 0; rr < 4; ++rr)
            C[(size_t)(m0 + mb * 128 + wr * 64 + fi * 16 + lhi * 4 + rr) * N_TOT
              + (n0 + nb * 128 + wc * 32 + fj * 16 + llo)] = acc[mb][nb][fi][fj][rr];
}

// ---- fi softmax-weighted reduction over s (chunked partials + atomics) ----
__global__ void k_fireduce(const float* __restrict__ Cfi, const float* __restrict__ a1v,
                           const float* __restrict__ c0, const int* __restrict__ seq_lens,
                           float* __restrict__ denom, float* __restrict__ cacc,
                           int sbase, int send) {
  int id = blockIdx.x * 256 + threadIdx.x;       // b*512+h
  int b = id >> 9, h = id & 511;
  int len = seq_lens[b * sl_stride(seq_lens)];
  int lim = (send < len) ? send : len;
  int s0 = sbase + blockIdx.y * 64;
  if (s0 >= lim) return;
  int s1 = (s0 + 64 < lim) ? s0 + 64 : lim;
  float a = a1v[id];
  float d = 0.f, ca = 0.f;
  for (int s = s0; s < s1; ++s) {
    size_t m = (size_t)(s * 32 + b);
    size_t ml = (size_t)((s - sbase) * 32 + b);
    float e = __expf(sigm(Cfi[ml * 512 + h] + a));
    d += e;
    ca += e * c0[m * 512 + h];
  }
  atomicAdd(&denom[id], d);
  atomicAdd(&cacc[id], ca);
}

// ---- global cell: c_g, h_g → out row S ----
__global__ void k_global(const float* __restrict__ sg0, const float* __restrict__ sg2,
                         const float* __restrict__ c0, const float* __restrict__ denom,
                         const float* __restrict__ cacc, float* __restrict__ out) {
  int id = blockIdx.x * 256 + threadIdx.x;       // 16384
  float fg = sigm(sg0[id]);
  float og = sigm(sg2[id]);
  float cg1 = c0[(size_t)HG_ROW + id];
  float dn = denom[id];
  float cg = fg * cg1 + cacc[id] / (dn > 0.f ? dn : 1.f);
  float hg = og * tanh_(cg);
  out[(size_t)HG_ROW + id] = hg;
  out[(size_t)CT_BASE + HG_ROW + id] = cg;
}

// ---- window epilogue: gates softmax-5, c_w, h_w ----
__global__ void k_epilogue(const float* __restrict__ Cch, const float* __restrict__ Vb,
                           const float* __restrict__ c0, const int* __restrict__ seq_lens,
                           float* __restrict__ out, int mbase) {
  int idx = blockIdx.x * 256 + threadIdx.x;      // chunk-local (m,h)
  int ml = idx >> 9, h = idx & 511;
  int mg = mbase + ml;
  int s = mg >> 5, b = mg & 31;
  int len = seq_lens[b * sl_stride(seq_lens)];
  float pre[7];
#pragma unroll
  for (int g = 0; g < 7; ++g)
    pre[g] = Cch[(size_t)ml * N_TOT + g * 512 + h] + Vb[(size_t)(g * 32 + b) * 512 + h];
  float i_ = sigm(pre[0]);
  float l_ = sigm(pre[1]);
  float r_ = sigm(pre[2]);
  float f_ = sigm(pre[3]);
  float sg = sigm(pre[4]);
  float o_ = sigm(pre[5]);
  float u_ = tanh_(pre[6]);
  float el = __expf(l_), ef = __expf(f_), er = __expf(r_), es = __expf(sg), ei = __expf(i_);
  float inv = 1.f / (el + ef + er + es + ei);
  float cw = 0.f;
  if (s < len) {
    float cl = (s >= 1) ? c0[(size_t)(mg - 32) * 512 + h] : 0.f;
    float cc = c0[(size_t)mg * 512 + h];
    float cr = (s + 1 < S_LEN && s + 1 < len) ? c0[(size_t)(mg + 32) * 512 + h] : 0.f;
    float cg1 = c0[(size_t)HG_ROW + b * 512 + h];
    cw = (el * cl + ef * cc + er * cr + es * cg1 + ei * u_) * inv;
  }
  float hw = o_ * tanh_(cw);
  size_t oi = (size_t)mg * 512 + h;
  out[oi] = hw;
  out[(size_t)CT_BASE + oi] = cw;
}

extern "C" void kernel_launch(void* const* d_in, const int* in_sizes, int n_in,
                              void* d_out, int out_size, void* d_ws, size_t ws_size,
                              hipStream_t stream) {
  const float* seqs = (const float*)d_in[0];
  const int* seq_lens = (const int*)d_in[1];
  const float* h0 = (const float*)d_in[2];
  const float* c0 = (const float*)d_in[3];
  const float* Ww = (const float*)d_in[4];
  const float* Wu = (const float*)d_in[5];
  const float* Wv = (const float*)d_in[6];
  const float* Wb = (const float*)d_in[7];
  const float* Sw = (const float*)d_in[8];
  const float* Su = (const float*)d_in[9];
  const float* Sb = (const float*)d_in[10];
  float* out = (float*)d_out;

  // ---- workspace layout (fixed ~49.7 MB) + adaptive C chunk ----
  char* ws = (char*)d_ws;
  size_t off = 0;
  float* denom = (float*)(ws + off); off += 16384 * 4;   // zeroed together:
  float* cacc  = (float*)(ws + off); off += 16384 * 4;   // denom, cacc, hhat
  float* hhat  = (float*)(ws + off); off += 16384 * 4;
  float* sg0  = (float*)(ws + off); off += 16384 * 4;
  float* sg2  = (float*)(ws + off); off += 16384 * 4;
  float* a1v  = (float*)(ws + off); off += 16384 * 4;
  float* Vb   = (float*)(ws + off); off += (size_t)7 * 16384 * 4;
  u16* hpad  = (u16*)(ws + off); off += (size_t)16448 * 512 * 2;   // 16.84 MB
  u16* seqsb = (u16*)(ws + off); off += (size_t)16384 * 512 * 2;   // 16.78 MB
  u16* Bcat  = (u16*)(ws + off); off += (size_t)3584 * 2048 * 2;   // 14.68 MB
  u16* Bfi   = (u16*)(ws + off); off += (size_t)512 * 512 * 2;     //  0.52 MB
  float* Cbig = (float*)(ws + off);

  size_t avail = (ws_size > off) ? (ws_size - off) : 0;
  int chunk_rows = (int)(avail / ((size_t)N_TOT * 4));
  chunk_rows = (chunk_rows / 256) * 256;         // 256-row tiles for gemm8
  if (chunk_rows > 4096) chunk_rows = 4096;
  if (chunk_rows < 256) chunk_rows = 256;
  int fi_rows = 7 * chunk_rows;                  // same byte budget at ldc=512
  if (fi_rows > 16384) fi_rows = 16384;

  prep_hpad<<<4112, 256, 0, stream>>>(h0, seq_lens, hpad);
  prep_seqs<<<4096, 256, 0, stream>>>(seqs, seqsb);
  prep_bcat<<<3584, 256, 0, stream>>>(Ww, Wu, Bcat);
  prep_bfi<<<128, 256, 0, stream>>>(Su, Bfi);
  k_zero<<<192, 256, 0, stream>>>(denom, 49152);          // denom+cacc+hhat
  k_hhat<<<dim3(64, 16), 256, 0, stream>>>(hpad, hhat);
  k_small<<<40960, 256, 0, stream>>>(h0, Sw, Su, Sb, Wv, Wb, hhat, sg0, sg2, a1v, Vb);

  // fi GEMM (16384 x 512) = h_w1 @ Su[1]^T, chunked over rows (old 128^2 kernel)
  GemmSrc gfi;
  gfi.a[0] = hpad + 32 * 512; gfi.b[0] = Bfi; gfi.bld[0] = 512; gfi.bcol[0] = 0;
  for (int fb = 0; fb < 16384; fb += fi_rows) {
    int rows = (fi_rows < 16384 - fb) ? fi_rows : (16384 - fb);
    gemm_kernel<<<dim3(4, rows / 128), 256, 0, stream>>>(gfi, Cbig, 512, 1, fb);
    int sbase = fb / 32, scnt = rows / 32;
    k_fireduce<<<dim3(64, (scnt + 63) / 64), 256, 0, stream>>>(
        Cbig, a1v, c0, seq_lens, denom, cacc, sbase, sbase + scnt);
  }
  k_global<<<64, 256, 0, stream>>>(sg0, sg2, c0, denom, cacc, out);

  // main GEMM: 8-phase 256^2 kernel; K = {h_w1[s-1], h_w1[s], h_w1[s+1], seqs} x Bcat
  for (int mb = 0; mb < 16384; mb += chunk_rows) {
    int rows = (chunk_rows < 16384 - mb) ? chunk_rows : (16384 - mb);
    gemm8_kernel<<<dim3(14, rows / 256), 512, 0, stream>>>(hpad, seqsb, Bcat, Cbig, mb, 32);
    k_epilogue<<<rows * 2, 256, 0, stream>>>(Cbig, Vb, c0, seq_lens, out, mb);
  }
}